// Round 3
// baseline (308.593 us; speedup 1.0000x reference)
//
#include <hip/hip_runtime.h>
#include <math.h>

// Sparsemax over rows: out = max(z - tau, 0), tau s.t. sum(max(z - tau, 0)) = 1.
// One block per row; row (4096 fp32) held entirely in registers (16/thread).
//
// tau solve (round 2, kept): f(zmax-1) >= 1 so tau is in [zmax-1, zmax]; only
// elements with z > zmax-1 (~5-15 per row for this data) matter. They are
// compacted to LDS and tau is computed in closed form (no sort/bisection):
// tau = max over valid candidates of (s_i-1)/n_i with n_i = #{c_j >= c_i},
// s_i = sum{c_j >= c_i}, valid iff 1 + n_i*c_i > s_i.
//
// Round 3 lever: memory-level parallelism in the load phase. Previously each
// float4/int4 pair was consumed by the select immediately -> only 2 KB
// outstanding per wave and 4 full latency round-trips (measured 2.4 TB/s,
// 30% of peak, no pipe busy = latency-bound). Now all 8 loads (8 KB/wave)
// are issued into separate register arrays before any select, giving one
// round-trip and 4x the outstanding bytes. VGPR stays <= 64 (occupancy 8
// blocks/CU preserved).

constexpr int S   = 4096;
constexpr int TPB = 256;
constexpr int VPT = S / TPB;   // 16 values per thread
constexpr int NW  = TPB / 64;  // 4 waves per block
constexpr int CAP = 1024;      // LDS candidate capacity (fallback beyond)

#define NEGBIG (-1e30f)

__global__ __launch_bounds__(TPB) void sparsemax_kernel(
    const float* __restrict__ scores,
    const int*   __restrict__ mask,
    float*       __restrict__ out)
{
    const int row  = blockIdx.x;
    const int tid  = threadIdx.x;
    const int lane = tid & 63;
    const int wid  = tid >> 6;

    const float* srow = scores + (size_t)row * S;
    const int*   mrow = mask   + (size_t)row * S;
    float*       orow = out    + (size_t)row * S;

    // ---- burst-issue all 8 loads (8 KB/wave in flight), select afterwards ----
    float4 sv[VPT / 4];
    int4   mv[VPT / 4];
    #pragma unroll
    for (int ch = 0; ch < VPT / 4; ++ch) {
        const int idx = ch * (TPB * 4) + tid * 4;
        sv[ch] = *reinterpret_cast<const float4*>(srow + idx);
    }
    #pragma unroll
    for (int ch = 0; ch < VPT / 4; ++ch) {
        const int idx = ch * (TPB * 4) + tid * 4;
        mv[ch] = *reinterpret_cast<const int4*>(mrow + idx);
    }

    float z[VPT];
    #pragma unroll
    for (int ch = 0; ch < VPT / 4; ++ch) {
        z[ch * 4 + 0] = mv[ch].x ? sv[ch].x : NEGBIG;
        z[ch * 4 + 1] = mv[ch].y ? sv[ch].y : NEGBIG;
        z[ch * 4 + 2] = mv[ch].z ? sv[ch].z : NEGBIG;
        z[ch * 4 + 3] = mv[ch].w ? sv[ch].w : NEGBIG;
    }

    __shared__ float red[NW];
    __shared__ float red2[NW];
    __shared__ float cand[CAP];
    __shared__ int cnt;
    if (tid == 0) cnt = 0;

    // ---- row max ----
    float mx = z[0];
    #pragma unroll
    for (int j = 1; j < VPT; ++j) mx = fmaxf(mx, z[j]);
    #pragma unroll
    for (int o = 1; o < 64; o <<= 1) mx = fmaxf(mx, __shfl_xor(mx, o, 64));
    if (lane == 0) red[wid] = mx;
    __syncthreads();                                   // A (also covers cnt=0)
    const float zmax = fmaxf(fmaxf(red[0], red[1]), fmaxf(red[2], red[3]));
    const float thr  = zmax - 1.0f;   // tau is in [thr, zmax]

    // ---- compact candidates (z > thr) into LDS ----
    #pragma unroll
    for (int j = 0; j < VPT; ++j) {
        if (z[j] > thr) {
            const int p = atomicAdd(&cnt, 1);
            if (p < CAP) cand[p] = z[j];
        }
    }
    __syncthreads();                                   // B (also frees red[])
    const int m = cnt;   // >= 1 (zmax is always a candidate)

    float tau;
    if (m <= CAP) {
        // ---- closed-form tau over candidates, no sort, no bisection ----
        float t = NEGBIG;
        for (int i = tid; i < m; i += TPB) {           // threads >= m skip
            const float ci = cand[i];
            float n = 0.0f, s = 0.0f;
            for (int j = 0; j < m; ++j) {              // same j all lanes: LDS broadcast
                const float cj = cand[j];
                if (cj >= ci) { n += 1.0f; s += cj; }
            }
            if (1.0f + n * ci > s) t = fmaxf(t, (s - 1.0f) / n);
        }
        #pragma unroll
        for (int o = 1; o < 64; o <<= 1) t = fmaxf(t, __shfl_xor(t, o, 64));
        if (lane == 0) red[wid] = t;
        __syncthreads();                               // C
        tau = fmaxf(fmaxf(red[0], red[1]), fmaxf(red[2], red[3]));
    } else {
        // ---- fallback: block-wide bisection (m > CAP; unreachable for this data) ----
        float lo = thr, hi = zmax;
        #pragma unroll 1
        for (int it = 0; it < 24; ++it) {
            const float mid = 0.5f * (lo + hi);
            float f = 0.0f;
            #pragma unroll
            for (int j = 0; j < VPT; ++j) f += fmaxf(z[j] - mid, 0.0f);
            #pragma unroll
            for (int o = 1; o < 64; o <<= 1) f += __shfl_xor(f, o, 64);
            __syncthreads();
            if (lane == 0) red[wid] = f;
            __syncthreads();
            f = (red[0] + red[1]) + (red[2] + red[3]);
            if (f > 1.0f) lo = mid; else hi = mid;
        }
        const float tc = 0.5f * (lo + hi);
        float s = 0.0f, k = 0.0f;
        #pragma unroll
        for (int j = 0; j < VPT; ++j) {
            if (z[j] > tc) { s += z[j]; k += 1.0f; }
        }
        #pragma unroll
        for (int o = 1; o < 64; o <<= 1) {
            s += __shfl_xor(s, o, 64);
            k += __shfl_xor(k, o, 64);
        }
        __syncthreads();
        if (lane == 0) { red[wid] = s; red2[wid] = k; }
        __syncthreads();
        s = (red[0] + red[1]) + (red[2] + red[3]);
        k = (red2[0] + red2[1]) + (red2[2] + red2[3]);
        if (k < 0.5f) { k = 1.0f; s = zmax; }          // unreachable guard
        tau = (s - 1.0f) / k;
    }

    // ---- write out ----
    #pragma unroll
    for (int ch = 0; ch < VPT / 4; ++ch) {
        const int idx = ch * (TPB * 4) + tid * 4;
        float4 o4;
        o4.x = fmaxf(z[ch * 4 + 0] - tau, 0.0f);
        o4.y = fmaxf(z[ch * 4 + 1] - tau, 0.0f);
        o4.z = fmaxf(z[ch * 4 + 2] - tau, 0.0f);
        o4.w = fmaxf(z[ch * 4 + 3] - tau, 0.0f);
        *reinterpret_cast<float4*>(orow + idx) = o4;
    }
}

extern "C" void kernel_launch(void* const* d_in, const int* in_sizes, int n_in,
                              void* d_out, int out_size, void* d_ws, size_t ws_size,
                              hipStream_t stream) {
    const float* scores = (const float*)d_in[0];
    const int*   mask   = (const int*)d_in[1];
    float*       out    = (float*)d_out;
    const int B = in_sizes[0] / S;  // 8192
    sparsemax_kernel<<<dim3(B), dim3(TPB), 0, stream>>>(scores, mask, out);
}